// Round 1
// baseline (2033.926 us; speedup 1.0000x reference)
//
#include <hip/hip_runtime.h>

// Problem constants (Go 19x19, B=256, history_factor=10)
#define BB 256
#define HH 19
#define WW 19
#define HW 361            // H*W
#define MAXM 3610         // MAX_MOVES

constexpr unsigned PERB = (unsigned)MAXM * (unsigned)HW;   // 1,303,210 elems per batch
constexpr unsigned TOT  = (unsigned)BB * PERB;             // 333,621,760
constexpr unsigned N4   = TOT / 4u;                        // 83,405,440 vec4s
// Output layout (floats, concatenated in reference return order)
constexpr unsigned OFF_BOARD = 0;                          // B*HW
constexpr unsigned OFF_HIST  = (unsigned)BB * HW;          // 92,416 (16B aligned)
constexpr unsigned OFF_KO    = OFF_HIST + TOT;             // B*2
constexpr unsigned OFF_PASS  = OFF_KO + 2u * BB;           // B
constexpr unsigned OFF_MV    = OFF_PASS + (unsigned)BB;    // B
constexpr unsigned OFF_PL    = OFF_MV + (unsigned)BB;      // B

__device__ __forceinline__ float state_of(float v) {
  // where(v==0, 0, where(v==1, 1, -1))
  return (v == 0.0f) ? 0.0f : ((v == 1.0f) ? 1.0f : -1.0f);
}

// Bulk history copy int32 -> float32, with the mv_c row replaced by board_state.
__global__ void __launch_bounds__(256) hist_kernel(
    const int* __restrict__ hist, const float* __restrict__ board,
    const int* __restrict__ move_count, float* __restrict__ out)
{
  unsigned i4 = blockIdx.x * 256u + threadIdx.x;
  if (i4 >= N4) return;
  unsigned e = i4 * 4u;
  int4 h = reinterpret_cast<const int4*>(hist)[i4];
  unsigned b = e / PERB;               // constant divisor -> magic mul
  unsigned j = e - b * PERB;
  float4 o;
  if (j + 3u < PERB) {
    // fast path: all 4 elements in batch b
    int mv = move_count[b];
    int mvc = mv < 0 ? 0 : (mv >= MAXM ? MAXM - 1 : mv);
    unsigned start = (unsigned)mvc * (unsigned)HW;
    bool valid = (mv < MAXM);
    const float* brd = board + (size_t)b * HW;
    unsigned d;
    d = j + 0u - start; o.x = (valid && d < (unsigned)HW) ? state_of(brd[d]) : (float)h.x;
    d = j + 1u - start; o.y = (valid && d < (unsigned)HW) ? state_of(brd[d]) : (float)h.y;
    d = j + 2u - start; o.z = (valid && d < (unsigned)HW) ? state_of(brd[d]) : (float)h.z;
    d = j + 3u - start; o.w = (valid && d < (unsigned)HW) ? state_of(brd[d]) : (float)h.w;
  } else {
    // batch-boundary vec4 (rare: per-batch size % 4 == 2): per-element
    float vals[4];
    int hv[4] = {h.x, h.y, h.z, h.w};
#pragma unroll
    for (int k = 0; k < 4; ++k) {
      unsigned ee = e + (unsigned)k;
      unsigned bb = ee / PERB;
      unsigned jj = ee - bb * PERB;
      int mv = move_count[bb];
      int mvc = mv < 0 ? 0 : (mv >= MAXM ? MAXM - 1 : mv);
      unsigned start = (unsigned)mvc * (unsigned)HW;
      bool valid = (mv < MAXM);
      unsigned d = jj - start;
      vals[k] = (valid && d < (unsigned)HW) ? state_of(board[(size_t)bb * HW + d])
                                            : (float)hv[k];
    }
    o.x = vals[0]; o.y = vals[1]; o.z = vals[2]; o.w = vals[3];
  }
  reinterpret_cast<float4*>(out + OFF_HIST)[i4] = o;
}

// Per-batch board update, capture, ko, scalars. One block per batch.
__global__ void __launch_bounds__(128) small_kernel(
    const float* __restrict__ board, const int* __restrict__ cur,
    const int* __restrict__ ko_pts, const int* __restrict__ pass_cnt,
    const int* __restrict__ mvcnt, const int* __restrict__ positions,
    const int* __restrict__ roots, const int* __restrict__ colour,
    const int* __restrict__ cap_groups, const int* __restrict__ cap_sizes,
    const int* __restrict__ total_caps, float* __restrict__ out)
{
  int b = blockIdx.x;
  int t = threadIdx.x;

  int p0 = positions[2 * b], p1 = positions[2 * b + 1];
  bool is_pass = (p0 < 0) || (p1 < 0);
  bool play = !is_pass;
  int row = p0 < 0 ? 0 : (p0 > HH - 1 ? HH - 1 : p0);
  int col = p1 < 0 ? 0 : (p1 > WW - 1 ? WW - 1 : p1);
  int fp = row * WW + col;
  int cp = cur[b];
  int opp = 1 - cp;
  int cgbase = (b * HW + fp) * 4;
  int nr0 = cap_groups[cgbase + 0];
  int nr1 = cap_groups[cgbase + 1];
  int nr2 = cap_groups[cgbase + 2];
  int nr3 = cap_groups[cgbase + 3];

  for (int p = t; p < HW; p += blockDim.x) {
    float v = board[b * HW + p];
    float placed = (play && p == fp) ? (float)cp : v;
    int r = roots[b * HW + p];
    bool eq = (nr0 >= 0 && r == nr0) || (nr1 >= 0 && r == nr1) ||
              (nr2 >= 0 && r == nr2) || (nr3 >= 0 && r == nr3);
    bool cap = eq && (colour[b * HW + p] == opp) && play;
    out[OFF_BOARD + b * HW + p] = cap ? -1.0f : placed;
  }

  if (t == 0) {
    // ko from single-stone capture
    int tc = total_caps[b * HW + fp];
    bool single_cap = (tc == 1) && play;
    int s0 = cap_sizes[cgbase + 0];
    int s1 = cap_sizes[cgbase + 1];
    int s2 = cap_sizes[cgbase + 2];
    int s3 = cap_sizes[cgbase + 3];
    // argmax of (sizes==1): first index where true, else 0
    int dir = (s0 == 1) ? 0 : ((s1 == 1) ? 1 : ((s2 == 1) ? 2 : ((s3 == 1) ? 3 : 0)));
    const int offs[4] = {-WW, WW, -1, 1};
    int nbr = fp + offs[dir];
    // Python floor division / mod (nbr can be negative)
    int rko = (nbr >= 0) ? (nbr / WW) : -(((-nbr) + WW - 1) / WW);
    int cko = nbr - rko * WW;

    int okr, okc;
    if (is_pass) { okr = ko_pts[2 * b]; okc = ko_pts[2 * b + 1]; }
    else if (single_cap) { okr = rko; okc = cko; }
    else { okr = -1; okc = -1; }
    out[OFF_KO + 2 * b + 0] = (float)okr;
    out[OFF_KO + 2 * b + 1] = (float)okc;
    out[OFF_PASS + b] = (float)(is_pass ? pass_cnt[b] + 1 : 0);
    out[OFF_MV + b]   = (float)(mvcnt[b] + 1);
    out[OFF_PL + b]   = (float)(cp ^ 1);
  }
}

extern "C" void kernel_launch(void* const* d_in, const int* in_sizes, int n_in,
                              void* d_out, int out_size, void* d_ws, size_t ws_size,
                              hipStream_t stream) {
  const float* board      = (const float*)d_in[0];
  const int*   cur        = (const int*)d_in[1];
  const int*   ko_pts     = (const int*)d_in[2];
  const int*   pass_cnt   = (const int*)d_in[3];
  const int*   hist       = (const int*)d_in[4];
  const int*   mvcnt      = (const int*)d_in[5];
  const int*   positions  = (const int*)d_in[6];
  const int*   roots      = (const int*)d_in[7];
  const int*   colour     = (const int*)d_in[8];
  const int*   cap_groups = (const int*)d_in[9];
  const int*   cap_sizes  = (const int*)d_in[10];
  const int*   total_caps = (const int*)d_in[11];
  float* out = (float*)d_out;

  unsigned blocks = (N4 + 255u) / 256u;
  hipLaunchKernelGGL(hist_kernel, dim3(blocks), dim3(256), 0, stream,
                     hist, board, mvcnt, out);
  hipLaunchKernelGGL(small_kernel, dim3(BB), dim3(128), 0, stream,
                     board, cur, ko_pts, pass_cnt, mvcnt, positions, roots,
                     colour, cap_groups, cap_sizes, total_caps, out);
}